// Round 5
// baseline (405.799 us; speedup 1.0000x reference)
//
#include <hip/hip_runtime.h>
#include <math.h>

// Problem constants (from reference)
#define NN 100000          // nodes
#define LF 48              // features per node
#define NE 1600000         // edges
#define EDIMS 17           // edge_attr dim
#define MASKW 3125         // NN/32 bitmask words
#define CAP_E 16384        // per-level edge-list capacity (expected ~4.6k max level)
#define MAXLOC 12288       // active-node capacity (expected ~4.9k)
#define DEG_CAP 96         // per-node in-edge bucket capacity (mean deg 16; P(>96) ~ 1e-20)
#define SLCAP 4096         // bfs LDS frontier-list capacity (|S1| expected ~280)

static_assert(NN == MASKW * 32, "mask width");
static_assert(NE % 4 == 0, "int4 edge scan");

__device__ __forceinline__ float gelu_f(float x) {
    // jax.nn.gelu(approximate=False) = x * 0.5 * (1 + erf(x/sqrt(2)))
    return 0.5f * x * (1.0f + erff(x * 0.7071067811865475f));
}
__device__ __forceinline__ float sigm_f(float x) {
    return 1.0f / (1.0f + expf(-x));
}
__device__ __forceinline__ float wave_sum(float v) {
    #pragma unroll
    for (int off = 32; off > 0; off >>= 1) v += __shfl_down(v, off, 64);
    return __shfl(v, 0, 64);   // broadcast lane-0 total
}

// THE one full-edge scan: bucket edge ids by dst. Also folds zero-init of the two
// agg buffers (consumed only by later dispatches). cnt[] is pre-zeroed by memset.
__global__ void scatter_kernel(const int* __restrict__ dst, int* __restrict__ cnt,
                               int* __restrict__ bkt, float4* __restrict__ aggz)
{
    int tid = blockIdx.x * 256 + threadIdx.x;
    int nthr = (int)gridDim.x * 256;
    for (int i = tid; i < (2 * MAXLOC * LF) / 4; i += nthr)
        aggz[i] = make_float4(0.f, 0.f, 0.f, 0.f);
    long e0 = (long)tid * 4;
    if (e0 < NE) {             // NE%4==0 -> whole group in range
        int4 d4 = *(const int4*)(dst + e0);
        int dv[4] = { d4.x, d4.y, d4.z, d4.w };
        #pragma unroll
        for (int k = 0; k < 4; ++k) {
            int d = dv[k];
            int pos = atomicAdd(&cnt[d], 1);
            if (pos < DEG_CAP) bkt[d * DEG_CAP + pos] = (int)e0 + k;
        }
    }
}

// Single-block BFS over the buckets: 3 levels, edge lists, dedupe + loc assignment.
// Loc layout by construction: node0 = loc 0; S2 = locs [0,|S2|); S1 = locs [0,|S1|);
// S0 = locs [0,nloc). Downstream needs no masks -- active sets are loc ranges.
// counters: [0]=|E3| [1]=|E2| [2]=|E1| [3]=nloc [4]=|S1| [5]=|S2|
__global__ void __launch_bounds__(1024) bfs_kernel(
    const int* __restrict__ src, const int* __restrict__ cnt, const int* __restrict__ bkt,
    int4* __restrict__ lists, int* __restrict__ counters,
    int* __restrict__ n2l, int* __restrict__ l2n)
{
    __shared__ unsigned msk[MASKW];
    __shared__ int ls[SLCAP];
    __shared__ int sn[8];   // [0]=frontier size [1]=|E3| [2]=|E2| [3]=|E1| [4]=nloc
    int t = threadIdx.x;
    for (int i = t; i < MASKW; i += 1024) msk[i] = 0u;
    if (t < 8) sn[t] = 0;
    __syncthreads();
    if (t == 0) { ls[0] = 0; msk[0] = 1u; sn[0] = 1; }   // seed S2 with node 0
    __syncthreads();

    // Level 3: in-edges of node 0 -> E3 (slot0); S2 = {0} ∪ srcs
    int c0r = cnt[0]; if (c0r > DEG_CAP) c0r = DEG_CAP;
    for (int i = t; i < c0r; i += 1024) {
        int e = bkt[i];
        int s = src[e];
        int idx = atomicAdd(&sn[1], 1);
        if (idx < CAP_E) lists[idx] = make_int4(s, 0, e, 0);
        unsigned b = 1u << (s & 31);
        unsigned old = atomicOr(&msk[s >> 5], b);
        if (!(old & b)) { int j = atomicAdd(&sn[0], 1); if (j < SLCAP) ls[j] = s; }
    }
    __syncthreads();
    int nS2 = sn[0]; if (nS2 > SLCAP) nS2 = SLCAP;
    __syncthreads();

    // Level 2: in-edges of S2 -> E2 (slot1); S1 = S2 ∪ srcs (list keeps growing)
    for (int j = t; j < nS2 * DEG_CAP; j += 1024) {
        int i = j / DEG_CAP, slot = j % DEG_CAP;
        int u = ls[i];
        int cu = cnt[u]; if (cu > DEG_CAP) cu = DEG_CAP;
        if (slot < cu) {
            int e = bkt[u * DEG_CAP + slot];
            int s = src[e];
            int idx = atomicAdd(&sn[2], 1);
            if (idx < CAP_E) lists[CAP_E + idx] = make_int4(s, u, e, 0);
            unsigned b = 1u << (s & 31);
            unsigned old = atomicOr(&msk[s >> 5], b);
            if (!(old & b)) { int jj = atomicAdd(&sn[0], 1); if (jj < SLCAP) ls[jj] = s; }
        }
    }
    __syncthreads();
    int nS1 = sn[0]; if (nS1 > SLCAP) nS1 = SLCAP;
    // assign locs for S1 (loc = frontier-list index)
    for (int i = t; i < nS1; i += 1024) { int u = ls[i]; n2l[u] = i; l2n[i] = u; }
    if (t == 0) sn[4] = nS1;
    __syncthreads();

    // Level 1: in-edges of S1 -> E1 (slot2); new srcs get fresh locs
    for (int j = t; j < nS1 * DEG_CAP; j += 1024) {
        int i = j / DEG_CAP, slot = j % DEG_CAP;
        int u = ls[i];
        int cu = cnt[u]; if (cu > DEG_CAP) cu = DEG_CAP;
        if (slot < cu) {
            int e = bkt[u * DEG_CAP + slot];
            int s = src[e];
            int idx = atomicAdd(&sn[3], 1);
            if (idx < CAP_E) lists[2 * CAP_E + idx] = make_int4(s, u, e, 0);
            unsigned b = 1u << (s & 31);
            unsigned old = atomicOr(&msk[s >> 5], b);
            if (!(old & b)) {
                int loc = atomicAdd(&sn[4], 1);
                if (loc < MAXLOC) { n2l[s] = loc; l2n[loc] = s; }
            }
        }
    }
    __syncthreads();
    if (t == 0) {
        int a = sn[1]; counters[0] = (a > CAP_E) ? CAP_E : a;
        a = sn[2];     counters[1] = (a > CAP_E) ? CAP_E : a;
        a = sn[3];     counters[2] = (a > CAP_E) ? CAP_E : a;
        a = sn[4];     counters[3] = (a > MAXLOC) ? MAXLOC : a;
        counters[4] = nS1;
        counters[5] = nS2;
    }
}

// Per-edge loop-invariant MLP scalar, wave-cooperative (64 lanes, no LDS/syncthreads):
//   w0 = gelu(relu(gelu(ea@W1+b1)@W2+b2)@Wg+bg)@Ww + bw    (broadcast to all lanes)
__device__ float w0_compute(long e, const float* __restrict__ ea_g,
                            const float* __restrict__ W1, const float* __restrict__ b1,
                            const float* __restrict__ W2, const float* __restrict__ b2,
                            const float* __restrict__ Wg, const float* __restrict__ bg,
                            const float* __restrict__ Ww, const float* __restrict__ bw,
                            int lane)
{
    float ea = 0.f;
    if (lane < EDIMS) ea = ea_g[e * EDIMS + lane];
    float h1 = 0.f;
    if (lane < 48) {
        float acc = b1[lane];
        #pragma unroll
        for (int k = 0; k < EDIMS; ++k) acc += __shfl(ea, k, 64) * W1[k * 48 + lane];
        h1 = gelu_f(acc);
    }
    float h2 = 0.f;
    if (lane < 48) {
        float acc = b2[lane];
        #pragma unroll 8
        for (int k = 0; k < 48; ++k) acc += __shfl(h1, k, 64) * W2[k * 48 + lane];
        h2 = fmaxf(acc, 0.f);
    }
    float part = 0.f;
    if (lane < 48) {
        float acc = bg[lane];
        #pragma unroll 8
        for (int k = 0; k < 48; ++k) acc += __shfl(h2, k, 64) * Wg[k * 48 + lane];
        part = gelu_f(acc) * Ww[lane];
    }
    return wave_sum(part) + bw[0];
}

// Fused: (a) init X0/VA for locs < |S1| (the only nodes whose state is ever read);
// (b) per-edge w0 for all 3 lists; E1 edges additionally do the iter-1 aggregation
// directly from RAW inputs (x0[src]=nodes*valid, mv0[src]=mean(valid)); E2/E3 entries
// are remapped to local ids for the tail.
__global__ void fused_kernel(const int* __restrict__ counters, const int* __restrict__ l2n,
                             const int* __restrict__ n2l,
                             const float* __restrict__ nodes, const float* __restrict__ valid,
                             float* __restrict__ X0, float* __restrict__ VA,
                             int4* __restrict__ lists, const float* __restrict__ ea_g,
                             const float* __restrict__ W1, const float* __restrict__ b1,
                             const float* __restrict__ W2, const float* __restrict__ b2,
                             const float* __restrict__ Wg, const float* __restrict__ bg,
                             const float* __restrict__ Ww, const float* __restrict__ bw,
                             float* __restrict__ agg0)
{
    int tid = blockIdx.x * 256 + threadIdx.x;
    int nthr = (int)gridDim.x * 256;
    int nS1 = counters[4]; if (nS1 > MAXLOC) nS1 = MAXLOC;
    for (int loc = tid; loc < nS1; loc += nthr) {
        int node = l2n[loc];
        const float4* nv = (const float4*)(valid + (size_t)node * LF);
        const float4* nx = (const float4*)(nodes + (size_t)node * LF);
        float4* X0v = (float4*)(X0 + (size_t)loc * LF);
        float4* V0v = (float4*)(VA + (size_t)loc * LF);
        #pragma unroll
        for (int k = 0; k < 12; ++k) {
            float4 v = nv[k], x = nx[k];
            x.x *= v.x; x.y *= v.y; x.z *= v.z; x.w *= v.w;
            X0v[k] = x; V0v[k] = v;
        }
    }
    int c0 = counters[0]; c0 = (c0 > CAP_E) ? CAP_E : c0;
    int c1 = counters[1]; c1 = (c1 > CAP_E) ? CAP_E : c1;
    int c2 = counters[2]; c2 = (c2 > CAP_E) ? CAP_E : c2;
    int total = c0 + c1 + c2;
    int lane = tid & 63;
    for (int g = tid >> 6; g < total; g += (nthr >> 6)) {
        int4* entp;
        bool isE1 = false;
        if (g < c0)           entp = lists + g;
        else if (g < c0 + c1) entp = lists + CAP_E + (g - c0);
        else                { entp = lists + 2 * CAP_E + (g - c0 - c1); isE1 = true; }
        int4 ent = *entp;
        float w0 = w0_compute((long)ent.z, ea_g, W1, b1, W2, b2, Wg, bg, Ww, bw, lane);
        if (isE1) {
            int s = ent.x;                          // global node id
            int dl = n2l[ent.y]; if ((unsigned)dl >= MAXLOC) dl = 0;
            float v = 0.f, x = 0.f;
            if (lane < 48) {
                v = valid[(size_t)s * LF + lane];
                x = nodes[(size_t)s * LF + lane] * v;
            }
            float mv = wave_sum(v) * (1.0f / 48.0f);
            float sg = sigm_f(mv * w0);
            if (lane < 48) atomicAdd(&agg0[dl * LF + lane], sg * x);
        } else if (lane == 0) {
            int sl = n2l[ent.x]; if ((unsigned)sl >= MAXLOC) sl = 0;
            int dl = n2l[ent.y]; if ((unsigned)dl >= MAXLOC) dl = 0;
            *entp = make_int4(sl, dl, ent.z, __float_as_int(w0));
        }
    }
}

// ---- single-block tail: upd1 -> agg2 -> upd2 -> agg3 -> upd3 -> out ----
// Wave-per-node (lane = feature) coalesced rows. Active sets are loc RANGES:
// iter-1 update over locs [0,|S1|); iter-2 update over locs [0,|S2|); node0 = loc 0.
__global__ void __launch_bounds__(1024) tail_kernel(
    const int* __restrict__ counters,
    const int4* __restrict__ lists, const float* __restrict__ X0,
    float* __restrict__ XA, float* __restrict__ XB,
    float* __restrict__ VA, float* __restrict__ VB,
    float* __restrict__ MVA, float* __restrict__ MVB,
    const float* __restrict__ agg0, float* __restrict__ agg1b,
    const float* __restrict__ Wf, const float* __restrict__ bf, float* __restrict__ out)
{
    __shared__ float agg3s[LF];
    int tid = threadIdx.x;
    if (tid < LF) agg3s[tid] = 0.f;
    __syncthreads();

    int c1n = counters[4]; if (c1n > MAXLOC) c1n = MAXLOC;   // |S1|
    int c2n = counters[5]; if (c2n > MAXLOC) c2n = MAXLOC;   // |S2|
    int wave = tid >> 6, lane = tid & 63;
    float wf0 = Wf[0], wf1 = Wf[1], wf2 = Wf[2], bfs = bf[0];

    // iter-1 update: locs [0,|S1|); X0/VA -> XA/VB/MVB  (Xp == Xorig == X0 here)
    for (int loc = wave; loc < c1n; loc += 16) {
        float nh = 0.f, xo = 0.f, vp = 0.f;
        if (lane < 48) {
            nh = agg0[loc * LF + lane];
            xo = X0[loc * LF + lane];
            vp = VA[loc * LF + lane];
        }
        float nv = 1.0f - vp;
        float m = sigm_f(nh * wf0 + xo * wf1 + nv * wf2 + bfs);
        float xn = (1.0f - m) * xo + nv * m * nh;
        float vn = ((xo != xn) || (vp > 0.f)) ? 1.0f : 0.0f;
        if (lane == 0) vn = 0.0f;
        if (lane < 48) { XA[loc * LF + lane] = xn; VB[loc * LF + lane] = vn; }
        float s = (lane < 48) ? vn : 0.f;
        #pragma unroll
        for (int off = 32; off > 0; off >>= 1) s += __shfl_down(s, off, 64);
        if (lane == 0) MVB[loc] = s * (1.0f / 48.0f);
    }
    __syncthreads();

    // iter-2 aggregation: E2 (slot1, local ids), wave-per-edge -> agg1b (~270 edges)
    int cE2 = counters[1]; if (cE2 > CAP_E) cE2 = CAP_E;
    for (int i = wave; i < cE2; i += 16) {
        int4 ent = lists[CAP_E + i];
        if ((unsigned)ent.x >= MAXLOC || (unsigned)ent.y >= MAXLOC) continue;
        float sg = sigm_f(MVB[ent.x] * __int_as_float(ent.w));
        if (lane < 48) atomicAdd(&agg1b[ent.y * LF + lane], sg * XA[ent.x * LF + lane]);
    }
    __syncthreads();

    // iter-2 update: locs [0,|S2|); XA/VB -> XB/VA/MVA  (Xorig = X0)
    for (int loc = wave; loc < c2n; loc += 16) {
        float nh = 0.f, xo = 0.f, vp = 0.f, xorig = 0.f;
        if (lane < 48) {
            nh = agg1b[loc * LF + lane];
            xo = XA[loc * LF + lane];
            vp = VB[loc * LF + lane];
            xorig = X0[loc * LF + lane];
        }
        float nv = 1.0f - vp;
        float m = sigm_f(nh * wf0 + xo * wf1 + nv * wf2 + bfs);
        float xn = (1.0f - m) * xo + nv * m * nh;
        float vn = ((xorig != xn) || (vp > 0.f)) ? 1.0f : 0.0f;
        if (lane == 0) vn = 0.0f;
        if (lane < 48) { XB[loc * LF + lane] = xn; VA[loc * LF + lane] = vn; }
        float s = (lane < 48) ? vn : 0.f;
        #pragma unroll
        for (int off = 32; off > 0; off >>= 1) s += __shfl_down(s, off, 64);
        if (lane == 0) MVA[loc] = s * (1.0f / 48.0f);
    }
    __syncthreads();

    // iter-3 aggregation: E3 (slot0, local ids), dst = node 0 -> LDS accumulator
    int cE3 = counters[0]; if (cE3 > CAP_E) cE3 = CAP_E;
    for (int i = wave; i < cE3; i += 16) {
        int4 ent = lists[i];
        if ((unsigned)ent.x >= MAXLOC) continue;
        float sg = sigm_f(MVA[ent.x] * __int_as_float(ent.w));
        if (lane < 48) atomicAdd(&agg3s[lane], sg * XB[ent.x * LF + lane]);
    }
    __syncthreads();

    // iter-3 update for node 0 (= loc 0 by construction) -> output row
    if (tid < 48) {
        float nh = agg3s[tid];
        float xo = XB[tid];          // loc 0 row
        float vp = VA[tid];
        float nv = 1.0f - vp;
        float m = sigm_f(nh * wf0 + xo * wf1 + nv * wf2 + bfs);
        out[tid] = (1.0f - m) * xo + nv * m * nh;
    }
}

extern "C" void kernel_launch(void* const* d_in, const int* in_sizes, int n_in,
                              void* d_out, int out_size, void* d_ws, size_t ws_size,
                              hipStream_t stream)
{
    (void)in_sizes; (void)n_in; (void)out_size;
    const float* nodes = (const float*)d_in[0];
    const int*   eidx  = (const int*)d_in[1];     // (2,E) int32
    const float* eattr = (const float*)d_in[2];
    const float* valid = (const float*)d_in[3];
    // d_in[4]=r, d_in[5]=fx unused by reference
    const float* W1 = (const float*)d_in[6];
    const float* b1 = (const float*)d_in[7];
    const float* W2 = (const float*)d_in[8];
    const float* b2 = (const float*)d_in[9];
    const float* Wg = (const float*)d_in[10];
    const float* bg = (const float*)d_in[11];
    const float* Ww = (const float*)d_in[12];
    const float* bw = (const float*)d_in[13];
    const float* Wf = (const float*)d_in[14];
    const float* bf = (const float*)d_in[15];
    const int* src = eidx;
    const int* dst = eidx + NE;

    char* ws = (char*)d_ws;
    size_t off = 0;
    auto alloc = [&](size_t bytes) -> char* {
        char* p = ws + off;
        off += (bytes + 255) & ~(size_t)255;
        return p;
    };
    // counters + cnt contiguous -> single hipMemsetAsync covers both
    char*     zb = alloc(256 + (size_t)NN * 4);
    int*      counters = (int*)zb;                // [0..5], see bfs_kernel
    int*      cnt = (int*)(zb + 256);             // per-node in-degree
    int*      bkt = (int*)alloc((size_t)NN * DEG_CAP * 4);   // 38.4 MB edge-id buckets
    int*      n2l = (int*)alloc((size_t)NN * 4);
    int*      l2n = (int*)alloc((size_t)MAXLOC * 4);
    int4*     lists = (int4*)alloc((size_t)3 * CAP_E * 16); // slot0=E3, slot1=E2, slot2=E1
    float*    X0 = (float*)alloc((size_t)MAXLOC * LF * 4);
    float*    XA = (float*)alloc((size_t)MAXLOC * LF * 4);
    float*    XB = (float*)alloc((size_t)MAXLOC * LF * 4);
    float*    VA = (float*)alloc((size_t)MAXLOC * LF * 4);
    float*    VB = (float*)alloc((size_t)MAXLOC * LF * 4);
    float*    MVA = (float*)alloc((size_t)MAXLOC * 4);
    float*    MVB = (float*)alloc((size_t)MAXLOC * 4);
    float*    agg = (float*)alloc((size_t)2 * MAXLOC * LF * 4); // agg0 | agg1b
    if (off > ws_size) return;   // ~58 MB needed; fail loudly rather than corrupt
    float* agg0  = agg;
    float* agg1b = agg + MAXLOC * LF;

    hipMemsetAsync(zb, 0, 256 + (size_t)NN * 4, stream);

    // ONE full-edge scan: bucket edges by dst (agg zero-init folded in).
    scatter_kernel<<<NE / 4 / 256, 256, 0, stream>>>(dst, cnt, bkt, (float4*)agg);
    // 3-level backward BFS over buckets + loc assignment (single block, tiny).
    bfs_kernel<<<1, 1024, 0, stream>>>(src, cnt, bkt, lists, counters, n2l, l2n);
    // init + per-edge w0 + iter-1 aggregation.
    fused_kernel<<<1024, 256, 0, stream>>>(counters, l2n, n2l, nodes, valid,
                                           X0, VA, lists, eattr,
                                           W1, b1, W2, b2, Wg, bg, Ww, bw, agg0);
    // iterations 1-3 updates/aggregations + output.
    tail_kernel<<<1, 1024, 0, stream>>>(counters, lists, X0,
                                        XA, XB, VA, VB, MVA, MVB,
                                        agg0, agg1b, Wf, bf, (float*)d_out);
}

// Round 6
// 356.045 us; speedup vs baseline: 1.1397x; 1.1397x over previous
//
#include <hip/hip_runtime.h>
#include <math.h>

// Problem constants (from reference)
#define NN 100000          // nodes
#define LF 48              // features per node
#define NE 1600000         // edges
#define EDIMS 17           // edge_attr dim
#define MASKW 3125         // NN/32 bitmask words
#define CAP_E 16384        // per-level edge-list capacity (expected ~4.6k max level)
#define NBKT 12500         // coarse buckets: bucket = node >> 3 (8 nodes/bucket)
#define BCAP 256           // per-bucket capacity (mean 128; P(overflow) ~ 1e-21)
#define SLCAP 4096         // S1 node capacity (expected ~280)
#define MAXLOC SLCAP       // loc space = S1 prefix numbering

static_assert(NN == MASKW * 32, "mask width");
static_assert(NN == NBKT * 8, "bucket shift");
static_assert(NE % 4 == 0, "int4 edge scan");

__device__ __forceinline__ float gelu_f(float x) {
    // jax.nn.gelu(approximate=False) = x * 0.5 * (1 + erf(x/sqrt(2)))
    return 0.5f * x * (1.0f + erff(x * 0.7071067811865475f));
}
__device__ __forceinline__ float sigm_f(float x) {
    return 1.0f / (1.0f + expf(-x));
}
__device__ __forceinline__ float wave_sum(float v) {
    #pragma unroll
    for (int off = 32; off > 0; off >>= 1) v += __shfl_down(v, off, 64);
    return __shfl(v, 0, 64);   // broadcast lane-0 total
}

// THE one full-edge scan: append (e,dst) records to coarse dst-buckets (L2-resident
// working set -> no write-allocate blowup), capture E3 (dst==0) inline, and fold
// zero-init of the agg buffers. bcnt[] and counters[] pre-zeroed by memset.
__global__ void scatter_kernel(const int* __restrict__ src, const int* __restrict__ dst,
                               int* __restrict__ bcnt, int2* __restrict__ bkt,
                               float4* __restrict__ aggz,
                               int4* __restrict__ list0, int* __restrict__ counters)
{
    int tid = blockIdx.x * 256 + threadIdx.x;
    int nthr = (int)gridDim.x * 256;
    for (int i = tid; i < (2 * MAXLOC * LF) / 4; i += nthr)
        aggz[i] = make_float4(0.f, 0.f, 0.f, 0.f);
    long e0 = (long)tid * 4;
    if (e0 < NE) {             // NE%4==0 -> whole group in range
        int4 d4 = *(const int4*)(dst + e0);
        int dv[4] = { d4.x, d4.y, d4.z, d4.w };
        #pragma unroll
        for (int k = 0; k < 4; ++k) {
            int d = dv[k];
            int e = (int)e0 + k;
            int b = d >> 3;
            int pos = atomicAdd(&bcnt[b], 1);
            if (pos < BCAP) bkt[b * BCAP + pos] = make_int2(e, d);
            if (d == 0) {      // E3 capture (S3 = {0})
                int s = src[e];
                int idx = atomicAdd(&counters[0], 1);
                if (idx < CAP_E) list0[idx] = make_int4(s, 0, e, 0);
            }
        }
    }
}

// Level-2 (single block): S2 = {0} ∪ src(E3) (dedup); scan buckets of S2 nodes for
// E2 edges; S1 = S2 ∪ src(E2); assign locs (prefix order: node0=0, S2 prefix, S1
// prefix); write S1 mask + n2l/l2n; rewrite E3/E2 entries to LOCAL ids.
// counters: [0]=|E3| [1]=|E2| [2]=|E1| [3]=nloc [4]=|S1| [5]=|S2|
__global__ void __launch_bounds__(1024) lvl2_kernel(
    const int* __restrict__ src, const int* __restrict__ bcnt, const int2* __restrict__ bkt,
    int4* __restrict__ lists, int* __restrict__ counters,
    int* __restrict__ n2l, int* __restrict__ l2n, unsigned* __restrict__ S1m)
{
    __shared__ unsigned msk[MASKW];
    __shared__ int ls[SLCAP];
    __shared__ int sn[2];   // [0]=|ls| [1]=|E2|
    int t = threadIdx.x;
    for (int i = t; i < MASKW; i += 1024) msk[i] = 0u;
    if (t < 2) sn[t] = 0;
    __syncthreads();
    if (t == 0) { ls[0] = 0; msk[0] = 1u; sn[0] = 1; }   // seed with node 0
    __syncthreads();

    // S2 from E3 srcs (scatter wrote (s_global, 0, e, 0))
    int cE3 = counters[0]; if (cE3 > CAP_E) cE3 = CAP_E;
    for (int i = t; i < cE3; i += 1024) {
        int s = lists[i].x;
        unsigned b = 1u << (s & 31);
        unsigned old = atomicOr(&msk[s >> 5], b);
        if (!(old & b)) { int j = atomicAdd(&sn[0], 1); if (j < SLCAP) ls[j] = s; }
    }
    __syncthreads();
    int nS2 = sn[0]; if (nS2 > SLCAP) nS2 = SLCAP;
    __syncthreads();

    // E2: scan buckets of S2 nodes; grow ls with new srcs (-> S1)
    for (int j = t; j < nS2 * BCAP; j += 1024) {
        int i = j >> 8, slot = j & (BCAP - 1);
        int u = ls[i];
        int b = u >> 3;
        int c = bcnt[b]; if (c > BCAP) c = BCAP;
        if (slot < c) {
            int2 r = bkt[b * BCAP + slot];
            if (r.y == u) {
                int e = r.x;
                int s = src[e];
                int idx = atomicAdd(&sn[1], 1);
                if (idx < CAP_E) lists[CAP_E + idx] = make_int4(s, u, e, 0);
                unsigned bb = 1u << (s & 31);
                unsigned old = atomicOr(&msk[s >> 5], bb);
                if (!(old & bb)) { int jj = atomicAdd(&sn[0], 1); if (jj < SLCAP) ls[jj] = s; }
            }
        }
    }
    __syncthreads();
    int nS1 = sn[0]; if (nS1 > SLCAP) nS1 = SLCAP;
    int cE2 = sn[1]; if (cE2 > CAP_E) cE2 = CAP_E;

    // locs (loc = ls index), S1 membership mask, n2l/l2n
    for (int i = t; i < nS1; i += 1024) { int u = ls[i]; n2l[u] = i; l2n[i] = u; }
    for (int w = t; w < MASKW; w += 1024) S1m[w] = msk[w];
    __syncthreads();   // block-wide visibility of n2l writes

    // rewrite E3/E2 to local ids (srcs ∈ S1, dsts ∈ S2 by construction)
    for (int i = t; i < cE3; i += 1024) {
        int4 en = lists[i];
        int sl = n2l[en.x]; if ((unsigned)sl >= MAXLOC) sl = 0;
        lists[i] = make_int4(sl, 0, en.z, 0);
    }
    for (int i = t; i < cE2; i += 1024) {
        int4 en = lists[CAP_E + i];
        int sl = n2l[en.x]; if ((unsigned)sl >= MAXLOC) sl = 0;
        int dl = n2l[en.y]; if ((unsigned)dl >= MAXLOC) dl = 0;
        lists[CAP_E + i] = make_int4(sl, dl, en.z, 0);
    }
    if (t == 0) {
        counters[1] = cE2;
        counters[3] = nS1;
        counters[4] = nS1;
        counters[5] = nS2;
    }
}

// Level-1 (wide): for each S1 node scan its bucket for in-edges -> E1 list.
// E1 records: (src GLOBAL id, dst LOCAL loc, e). No dedupe/loc assignment needed:
// level-1 srcs are only ever read from raw inputs in fused_kernel.
__global__ void lvl1_kernel(const int* __restrict__ src, const int* __restrict__ bcnt,
                            const int2* __restrict__ bkt, const int* __restrict__ l2n,
                            int4* __restrict__ list2, int* __restrict__ counters)
{
    int nS1 = counters[4]; if (nS1 > SLCAP) nS1 = SLCAP;
    int total = nS1 * BCAP;
    int tid = blockIdx.x * 256 + threadIdx.x;
    int nthr = (int)gridDim.x * 256;
    for (int g = tid; g < total; g += nthr) {
        int i = g >> 8, slot = g & (BCAP - 1);
        int u = l2n[i];
        int b = u >> 3;
        int c = bcnt[b]; if (c > BCAP) c = BCAP;
        if (slot < c) {
            int2 r = bkt[b * BCAP + slot];
            if (r.y == u) {
                int e = r.x;
                int s = src[e];
                int idx = atomicAdd(&counters[2], 1);
                if (idx < CAP_E) list2[idx] = make_int4(s, i, e, 0);
            }
        }
    }
}

// Per-edge loop-invariant MLP scalar, wave-cooperative (64 lanes, no LDS/syncthreads):
//   w0 = gelu(relu(gelu(ea@W1+b1)@W2+b2)@Wg+bg)@Ww + bw    (broadcast to all lanes)
__device__ float w0_compute(long e, const float* __restrict__ ea_g,
                            const float* __restrict__ W1, const float* __restrict__ b1,
                            const float* __restrict__ W2, const float* __restrict__ b2,
                            const float* __restrict__ Wg, const float* __restrict__ bg,
                            const float* __restrict__ Ww, const float* __restrict__ bw,
                            int lane)
{
    float ea = 0.f;
    if (lane < EDIMS) ea = ea_g[e * EDIMS + lane];
    float h1 = 0.f;
    if (lane < 48) {
        float acc = b1[lane];
        #pragma unroll
        for (int k = 0; k < EDIMS; ++k) acc += __shfl(ea, k, 64) * W1[k * 48 + lane];
        h1 = gelu_f(acc);
    }
    float h2 = 0.f;
    if (lane < 48) {
        float acc = b2[lane];
        #pragma unroll 8
        for (int k = 0; k < 48; ++k) acc += __shfl(h1, k, 64) * W2[k * 48 + lane];
        h2 = fmaxf(acc, 0.f);
    }
    float part = 0.f;
    if (lane < 48) {
        float acc = bg[lane];
        #pragma unroll 8
        for (int k = 0; k < 48; ++k) acc += __shfl(h2, k, 64) * Wg[k * 48 + lane];
        part = gelu_f(acc) * Ww[lane];
    }
    return wave_sum(part) + bw[0];
}

// Fused: (a) init X0/VA for locs < |S1| (the only node state ever read);
// (b) per-edge w0 for all 3 lists; E1 edges do the iter-1 aggregation directly from
// RAW inputs (x0[src]=nodes*valid, mv0[src]=mean(valid)); E2/E3 get w0 stored.
__global__ void fused_kernel(const int* __restrict__ counters, const int* __restrict__ l2n,
                             const float* __restrict__ nodes, const float* __restrict__ valid,
                             float* __restrict__ X0, float* __restrict__ VA,
                             int4* __restrict__ lists, const float* __restrict__ ea_g,
                             const float* __restrict__ W1, const float* __restrict__ b1,
                             const float* __restrict__ W2, const float* __restrict__ b2,
                             const float* __restrict__ Wg, const float* __restrict__ bg,
                             const float* __restrict__ Ww, const float* __restrict__ bw,
                             float* __restrict__ agg0)
{
    int tid = blockIdx.x * 256 + threadIdx.x;
    int nthr = (int)gridDim.x * 256;
    int nS1 = counters[4]; if (nS1 > MAXLOC) nS1 = MAXLOC;
    for (int loc = tid; loc < nS1; loc += nthr) {
        int node = l2n[loc];
        const float4* nv = (const float4*)(valid + (size_t)node * LF);
        const float4* nx = (const float4*)(nodes + (size_t)node * LF);
        float4* X0v = (float4*)(X0 + (size_t)loc * LF);
        float4* V0v = (float4*)(VA + (size_t)loc * LF);
        #pragma unroll
        for (int k = 0; k < 12; ++k) {
            float4 v = nv[k], x = nx[k];
            x.x *= v.x; x.y *= v.y; x.z *= v.z; x.w *= v.w;
            X0v[k] = x; V0v[k] = v;
        }
    }
    int c0 = counters[0]; c0 = (c0 > CAP_E) ? CAP_E : c0;
    int c1 = counters[1]; c1 = (c1 > CAP_E) ? CAP_E : c1;
    int c2 = counters[2]; c2 = (c2 > CAP_E) ? CAP_E : c2;
    int total = c0 + c1 + c2;
    int lane = tid & 63;
    for (int g = tid >> 6; g < total; g += (nthr >> 6)) {
        int4* entp;
        bool isE1 = false;
        if (g < c0)           entp = lists + g;
        else if (g < c0 + c1) entp = lists + CAP_E + (g - c0);
        else                { entp = lists + 2 * CAP_E + (g - c0 - c1); isE1 = true; }
        int4 ent = *entp;
        float w0 = w0_compute((long)ent.z, ea_g, W1, b1, W2, b2, Wg, bg, Ww, bw, lane);
        if (isE1) {
            int s = ent.x;                          // global node id
            int dl = ent.y; if ((unsigned)dl >= MAXLOC) dl = 0;   // local loc
            float v = 0.f, x = 0.f;
            if (lane < 48) {
                v = valid[(size_t)s * LF + lane];
                x = nodes[(size_t)s * LF + lane] * v;
            }
            float mv = wave_sum(v) * (1.0f / 48.0f);
            float sg = sigm_f(mv * w0);
            if (lane < 48) atomicAdd(&agg0[dl * LF + lane], sg * x);
        } else if (lane == 0) {
            entp->w = __float_as_int(w0);           // ids already local
        }
    }
}

// ---- single-block tail: upd1 -> agg2 -> upd2 -> agg3 -> upd3 -> out ----
// Wave-per-node (lane = feature) coalesced rows. Active sets are loc RANGES:
// iter-1 update over locs [0,|S1|); iter-2 update over locs [0,|S2|); node0 = loc 0.
__global__ void __launch_bounds__(1024) tail_kernel(
    const int* __restrict__ counters,
    const int4* __restrict__ lists, const float* __restrict__ X0,
    float* __restrict__ XA, float* __restrict__ XB,
    float* __restrict__ VA, float* __restrict__ VB,
    float* __restrict__ MVA, float* __restrict__ MVB,
    const float* __restrict__ agg0, float* __restrict__ agg1b,
    const float* __restrict__ Wf, const float* __restrict__ bf, float* __restrict__ out)
{
    __shared__ float agg3s[LF];
    int tid = threadIdx.x;
    if (tid < LF) agg3s[tid] = 0.f;
    __syncthreads();

    int c1n = counters[4]; if (c1n > MAXLOC) c1n = MAXLOC;   // |S1|
    int c2n = counters[5]; if (c2n > MAXLOC) c2n = MAXLOC;   // |S2|
    int wave = tid >> 6, lane = tid & 63;
    float wf0 = Wf[0], wf1 = Wf[1], wf2 = Wf[2], bfs = bf[0];

    // iter-1 update: locs [0,|S1|); X0/VA -> XA/VB/MVB  (Xp == Xorig == X0 here)
    for (int loc = wave; loc < c1n; loc += 16) {
        float nh = 0.f, xo = 0.f, vp = 0.f;
        if (lane < 48) {
            nh = agg0[loc * LF + lane];
            xo = X0[loc * LF + lane];
            vp = VA[loc * LF + lane];
        }
        float nv = 1.0f - vp;
        float m = sigm_f(nh * wf0 + xo * wf1 + nv * wf2 + bfs);
        float xn = (1.0f - m) * xo + nv * m * nh;
        float vn = ((xo != xn) || (vp > 0.f)) ? 1.0f : 0.0f;
        if (lane == 0) vn = 0.0f;
        if (lane < 48) { XA[loc * LF + lane] = xn; VB[loc * LF + lane] = vn; }
        float s = (lane < 48) ? vn : 0.f;
        #pragma unroll
        for (int off = 32; off > 0; off >>= 1) s += __shfl_down(s, off, 64);
        if (lane == 0) MVB[loc] = s * (1.0f / 48.0f);
    }
    __syncthreads();

    // iter-2 aggregation: E2 (slot1, local ids), wave-per-edge -> agg1b (~270 edges)
    int cE2 = counters[1]; if (cE2 > CAP_E) cE2 = CAP_E;
    for (int i = wave; i < cE2; i += 16) {
        int4 ent = lists[CAP_E + i];
        if ((unsigned)ent.x >= MAXLOC || (unsigned)ent.y >= MAXLOC) continue;
        float sg = sigm_f(MVB[ent.x] * __int_as_float(ent.w));
        if (lane < 48) atomicAdd(&agg1b[ent.y * LF + lane], sg * XA[ent.x * LF + lane]);
    }
    __syncthreads();

    // iter-2 update: locs [0,|S2|); XA/VB -> XB/VA/MVA  (Xorig = X0)
    for (int loc = wave; loc < c2n; loc += 16) {
        float nh = 0.f, xo = 0.f, vp = 0.f, xorig = 0.f;
        if (lane < 48) {
            nh = agg1b[loc * LF + lane];
            xo = XA[loc * LF + lane];
            vp = VB[loc * LF + lane];
            xorig = X0[loc * LF + lane];
        }
        float nv = 1.0f - vp;
        float m = sigm_f(nh * wf0 + xo * wf1 + nv * wf2 + bfs);
        float xn = (1.0f - m) * xo + nv * m * nh;
        float vn = ((xorig != xn) || (vp > 0.f)) ? 1.0f : 0.0f;
        if (lane == 0) vn = 0.0f;
        if (lane < 48) { XB[loc * LF + lane] = xn; VA[loc * LF + lane] = vn; }
        float s = (lane < 48) ? vn : 0.f;
        #pragma unroll
        for (int off = 32; off > 0; off >>= 1) s += __shfl_down(s, off, 64);
        if (lane == 0) MVA[loc] = s * (1.0f / 48.0f);
    }
    __syncthreads();

    // iter-3 aggregation: E3 (slot0, local ids), dst = node 0 -> LDS accumulator
    int cE3 = counters[0]; if (cE3 > CAP_E) cE3 = CAP_E;
    for (int i = wave; i < cE3; i += 16) {
        int4 ent = lists[i];
        if ((unsigned)ent.x >= MAXLOC) continue;
        float sg = sigm_f(MVA[ent.x] * __int_as_float(ent.w));
        if (lane < 48) atomicAdd(&agg3s[lane], sg * XB[ent.x * LF + lane]);
    }
    __syncthreads();

    // iter-3 update for node 0 (= loc 0 by construction) -> output row
    if (tid < 48) {
        float nh = agg3s[tid];
        float xo = XB[tid];          // loc 0 row
        float vp = VA[tid];
        float nv = 1.0f - vp;
        float m = sigm_f(nh * wf0 + xo * wf1 + nv * wf2 + bfs);
        out[tid] = (1.0f - m) * xo + nv * m * nh;
    }
}

extern "C" void kernel_launch(void* const* d_in, const int* in_sizes, int n_in,
                              void* d_out, int out_size, void* d_ws, size_t ws_size,
                              hipStream_t stream)
{
    (void)in_sizes; (void)n_in; (void)out_size;
    const float* nodes = (const float*)d_in[0];
    const int*   eidx  = (const int*)d_in[1];     // (2,E) int32
    const float* eattr = (const float*)d_in[2];
    const float* valid = (const float*)d_in[3];
    // d_in[4]=r, d_in[5]=fx unused by reference
    const float* W1 = (const float*)d_in[6];
    const float* b1 = (const float*)d_in[7];
    const float* W2 = (const float*)d_in[8];
    const float* b2 = (const float*)d_in[9];
    const float* Wg = (const float*)d_in[10];
    const float* bg = (const float*)d_in[11];
    const float* Ww = (const float*)d_in[12];
    const float* bw = (const float*)d_in[13];
    const float* Wf = (const float*)d_in[14];
    const float* bf = (const float*)d_in[15];
    const int* src = eidx;
    const int* dst = eidx + NE;

    char* ws = (char*)d_ws;
    size_t off = 0;
    auto alloc = [&](size_t bytes) -> char* {
        char* p = ws + off;
        off += (bytes + 255) & ~(size_t)255;
        return p;
    };
    // counters + bcnt contiguous -> single hipMemsetAsync covers both (~50 KB)
    char*     zb = alloc(256 + (size_t)NBKT * 4);
    int*      counters = (int*)zb;                // [0..5], see lvl2_kernel
    int*      bcnt = (int*)(zb + 256);            // per-bucket counts
    int2*     bkt = (int2*)alloc((size_t)NBKT * BCAP * 8);   // 25.6 MB (e,dst) records
    int*      n2l = (int*)alloc((size_t)NN * 4);
    int*      l2n = (int*)alloc((size_t)MAXLOC * 4);
    unsigned* S1m = (unsigned*)alloc(MASKW * 4);
    int4*     lists = (int4*)alloc((size_t)3 * CAP_E * 16); // slot0=E3, slot1=E2, slot2=E1
    float*    X0 = (float*)alloc((size_t)MAXLOC * LF * 4);
    float*    XA = (float*)alloc((size_t)MAXLOC * LF * 4);
    float*    XB = (float*)alloc((size_t)MAXLOC * LF * 4);
    float*    VA = (float*)alloc((size_t)MAXLOC * LF * 4);
    float*    VB = (float*)alloc((size_t)MAXLOC * LF * 4);
    float*    MVA = (float*)alloc((size_t)MAXLOC * 4);
    float*    MVB = (float*)alloc((size_t)MAXLOC * 4);
    float*    agg = (float*)alloc((size_t)2 * MAXLOC * LF * 4); // agg0 | agg1b
    if (off > ws_size) return;   // ~33 MB needed; fail loudly rather than corrupt
    float* agg0  = agg;
    float* agg1b = agg + MAXLOC * LF;

    hipMemsetAsync(zb, 0, 256 + (size_t)NBKT * 4, stream);

    // ONE full-edge scan: coarse dst-buckets + E3 capture + agg zero-init.
    scatter_kernel<<<NE / 4 / 256, 256, 0, stream>>>(src, dst, bcnt, bkt, (float4*)agg,
                                                     lists, counters);
    // Level 2: S2/S1 sets, locs, E2 list, local-id rewrite (single block, ~4k probes).
    lvl2_kernel<<<1, 1024, 0, stream>>>(src, bcnt, bkt, lists, counters, n2l, l2n, S1m);
    // Level 1: wide bucket scan of S1 nodes -> E1 list (~72k probes).
    lvl1_kernel<<<320, 256, 0, stream>>>(src, bcnt, bkt, l2n, lists + 2 * CAP_E, counters);
    // init + per-edge w0 + iter-1 aggregation from raw inputs.
    fused_kernel<<<1024, 256, 0, stream>>>(counters, l2n, nodes, valid,
                                           X0, VA, lists, eattr,
                                           W1, b1, W2, b2, Wg, bg, Ww, bw, agg0);
    // iterations 1-3 updates/aggregations + output.
    tail_kernel<<<1, 1024, 0, stream>>>(counters, lists, X0,
                                        XA, XB, VA, VB, MVA, MVB,
                                        agg0, agg1b, Wf, bf, (float*)d_out);
}

// Round 7
// 349.748 us; speedup vs baseline: 1.1603x; 1.0180x over previous
//
#include <hip/hip_runtime.h>
#include <math.h>

// Problem constants (from reference)
#define NN 100000          // nodes
#define LF 48              // features per node
#define NE 1600000         // edges
#define EDIMS 17           // edge_attr dim
#define MASKW 3125         // NN/32 bitmask words
#define CAP_E 16384        // per-level edge-list capacity (expected ~4.6k max level)
#define NBKT 12500         // coarse buckets: bucket = node >> 3 (8 nodes/bucket)
#define NPART 8            // XCD-private partitions (blockIdx & 7 ~ XCD id)
#define BCAPP 64           // per-partition bucket capacity (mean 16; P(>64) ~ 0)
#define SLCAP 4096         // S1 node capacity (expected ~280)
#define MAXLOC SLCAP       // loc space = S1 prefix numbering

static_assert(NN == MASKW * 32, "mask width");
static_assert(NN == NBKT * 8, "bucket shift");
static_assert(NE % 4 == 0, "int4 edge scan");
static_assert(NPART * BCAPP == 512, "probe index math");

__device__ __forceinline__ float gelu_f(float x) {
    // jax.nn.gelu(approximate=False) = x * 0.5 * (1 + erf(x/sqrt(2)))
    return 0.5f * x * (1.0f + erff(x * 0.7071067811865475f));
}
__device__ __forceinline__ float sigm_f(float x) {
    return 1.0f / (1.0f + expf(-x));
}
__device__ __forceinline__ float wave_sum(float v) {
    #pragma unroll
    for (int off = 32; off > 0; off >>= 1) v += __shfl_down(v, off, 64);
    return __shfl(v, 0, 64);   // broadcast lane-0 total
}

// THE one full-edge scan: append (e,dst) records to XCD-PRIVATE coarse dst-buckets.
// blockIdx&7 tracks the round-robin block->XCD assignment, so each partition's
// append front is written by one XCD only -> lines stay L2-resident, fill fully,
// write back once (kills the 8x cross-XCD write amplification seen in r6).
// Also captures E3 (dst==0) inline and folds agg zero-init.
__global__ void scatter_kernel(const int* __restrict__ src, const int* __restrict__ dst,
                               int* __restrict__ bcnt, int2* __restrict__ bkt,
                               float4* __restrict__ aggz,
                               int4* __restrict__ list0, int* __restrict__ counters)
{
    int part = blockIdx.x & (NPART - 1);
    int tid = blockIdx.x * 256 + threadIdx.x;
    int nthr = (int)gridDim.x * 256;
    for (int i = tid; i < (2 * MAXLOC * LF) / 4; i += nthr)
        aggz[i] = make_float4(0.f, 0.f, 0.f, 0.f);
    long e0 = (long)tid * 4;
    if (e0 < NE) {             // NE%4==0 -> whole group in range
        int4 d4 = *(const int4*)(dst + e0);
        int dv[4] = { d4.x, d4.y, d4.z, d4.w };
        #pragma unroll
        for (int k = 0; k < 4; ++k) {
            int d = dv[k];
            int e = (int)e0 + k;
            int base = part * NBKT + (d >> 3);
            int pos = atomicAdd(&bcnt[base], 1);
            if (pos < BCAPP) bkt[(size_t)base * BCAPP + pos] = make_int2(e, d);
            if (d == 0) {      // E3 capture (S3 = {0})
                int s = src[e];
                int idx = atomicAdd(&counters[0], 1);
                if (idx < CAP_E) list0[idx] = make_int4(s, 0, e, 0);
            }
        }
    }
}

// Level-2 (single block): S2 = {0} ∪ src(E3) (dedup); probe the 8 sub-buckets of
// each S2 node for E2 edges; S1 = S2 ∪ src(E2); assign locs (prefix order: node0=0,
// S2 prefix, S1 prefix); rewrite E3/E2 entries to LOCAL ids.
// counters: [0]=|E3| [1]=|E2| [2]=|E1| [3]=nloc [4]=|S1| [5]=|S2|
__global__ void __launch_bounds__(1024) lvl2_kernel(
    const int* __restrict__ src, const int* __restrict__ bcnt, const int2* __restrict__ bkt,
    int4* __restrict__ lists, int* __restrict__ counters,
    int* __restrict__ n2l, int* __restrict__ l2n)
{
    __shared__ unsigned msk[MASKW];
    __shared__ int ls[SLCAP];
    __shared__ int sn[2];   // [0]=|ls| [1]=|E2|
    int t = threadIdx.x;
    for (int i = t; i < MASKW; i += 1024) msk[i] = 0u;
    if (t < 2) sn[t] = 0;
    __syncthreads();
    if (t == 0) { ls[0] = 0; msk[0] = 1u; sn[0] = 1; }   // seed with node 0
    __syncthreads();

    // S2 from E3 srcs (scatter wrote (s_global, 0, e, 0))
    int cE3 = counters[0]; if (cE3 > CAP_E) cE3 = CAP_E;
    for (int i = t; i < cE3; i += 1024) {
        int s = lists[i].x;
        unsigned b = 1u << (s & 31);
        unsigned old = atomicOr(&msk[s >> 5], b);
        if (!(old & b)) { int j = atomicAdd(&sn[0], 1); if (j < SLCAP) ls[j] = s; }
    }
    __syncthreads();
    int nS2 = sn[0]; if (nS2 > SLCAP) nS2 = SLCAP;
    __syncthreads();

    // E2: probe 8 sub-buckets per S2 node; grow ls with new srcs (-> S1)
    for (int j = t; j < nS2 * NPART * BCAPP; j += 1024) {
        int i = j >> 9;                    // / (NPART*BCAPP)
        int part = (j >> 6) & (NPART - 1);
        int slot = j & (BCAPP - 1);
        int u = ls[i];
        int base = part * NBKT + (u >> 3);
        int c = bcnt[base]; if (c > BCAPP) c = BCAPP;
        if (slot < c) {
            int2 r = bkt[(size_t)base * BCAPP + slot];
            if (r.y == u) {
                int e = r.x;
                int s = src[e];
                int idx = atomicAdd(&sn[1], 1);
                if (idx < CAP_E) lists[CAP_E + idx] = make_int4(s, u, e, 0);
                unsigned bb = 1u << (s & 31);
                unsigned old = atomicOr(&msk[s >> 5], bb);
                if (!(old & bb)) { int jj = atomicAdd(&sn[0], 1); if (jj < SLCAP) ls[jj] = s; }
            }
        }
    }
    __syncthreads();
    int nS1 = sn[0]; if (nS1 > SLCAP) nS1 = SLCAP;
    int cE2 = sn[1]; if (cE2 > CAP_E) cE2 = CAP_E;

    // locs (loc = ls index), n2l/l2n
    for (int i = t; i < nS1; i += 1024) { int u = ls[i]; n2l[u] = i; l2n[i] = u; }
    __syncthreads();   // block-wide visibility of n2l writes

    // rewrite E3/E2 to local ids (srcs ∈ S1, dsts ∈ S2 by construction)
    for (int i = t; i < cE3; i += 1024) {
        int4 en = lists[i];
        int sl = n2l[en.x]; if ((unsigned)sl >= MAXLOC) sl = 0;
        lists[i] = make_int4(sl, 0, en.z, 0);
    }
    for (int i = t; i < cE2; i += 1024) {
        int4 en = lists[CAP_E + i];
        int sl = n2l[en.x]; if ((unsigned)sl >= MAXLOC) sl = 0;
        int dl = n2l[en.y]; if ((unsigned)dl >= MAXLOC) dl = 0;
        lists[CAP_E + i] = make_int4(sl, dl, en.z, 0);
    }
    if (t == 0) {
        counters[1] = cE2;
        counters[3] = nS1;
        counters[4] = nS1;
        counters[5] = nS2;
    }
}

// Level-1 (wide): probe the 8 sub-buckets of each S1 node -> E1 list.
// E1 records: (src GLOBAL id, dst LOCAL loc, e). No dedupe/loc assignment needed:
// level-1 srcs are only ever read from raw inputs in fused_kernel.
__global__ void lvl1_kernel(const int* __restrict__ src, const int* __restrict__ bcnt,
                            const int2* __restrict__ bkt, const int* __restrict__ l2n,
                            int4* __restrict__ list2, int* __restrict__ counters)
{
    int nS1 = counters[4]; if (nS1 > SLCAP) nS1 = SLCAP;
    int total = nS1 * NPART * BCAPP;
    int tid = blockIdx.x * 256 + threadIdx.x;
    int nthr = (int)gridDim.x * 256;
    for (int g = tid; g < total; g += nthr) {
        int i = g >> 9;
        int part = (g >> 6) & (NPART - 1);
        int slot = g & (BCAPP - 1);
        int u = l2n[i];
        int base = part * NBKT + (u >> 3);
        int c = bcnt[base]; if (c > BCAPP) c = BCAPP;
        if (slot < c) {
            int2 r = bkt[(size_t)base * BCAPP + slot];
            if (r.y == u) {
                int e = r.x;
                int s = src[e];
                int idx = atomicAdd(&counters[2], 1);
                if (idx < CAP_E) list2[idx] = make_int4(s, i, e, 0);
            }
        }
    }
}

// Per-edge loop-invariant MLP scalar, wave-cooperative (64 lanes, no LDS/syncthreads):
//   w0 = gelu(relu(gelu(ea@W1+b1)@W2+b2)@Wg+bg)@Ww + bw    (broadcast to all lanes)
__device__ float w0_compute(long e, const float* __restrict__ ea_g,
                            const float* __restrict__ W1, const float* __restrict__ b1,
                            const float* __restrict__ W2, const float* __restrict__ b2,
                            const float* __restrict__ Wg, const float* __restrict__ bg,
                            const float* __restrict__ Ww, const float* __restrict__ bw,
                            int lane)
{
    float ea = 0.f;
    if (lane < EDIMS) ea = ea_g[e * EDIMS + lane];
    float h1 = 0.f;
    if (lane < 48) {
        float acc = b1[lane];
        #pragma unroll
        for (int k = 0; k < EDIMS; ++k) acc += __shfl(ea, k, 64) * W1[k * 48 + lane];
        h1 = gelu_f(acc);
    }
    float h2 = 0.f;
    if (lane < 48) {
        float acc = b2[lane];
        #pragma unroll 8
        for (int k = 0; k < 48; ++k) acc += __shfl(h1, k, 64) * W2[k * 48 + lane];
        h2 = fmaxf(acc, 0.f);
    }
    float part = 0.f;
    if (lane < 48) {
        float acc = bg[lane];
        #pragma unroll 8
        for (int k = 0; k < 48; ++k) acc += __shfl(h2, k, 64) * Wg[k * 48 + lane];
        part = gelu_f(acc) * Ww[lane];
    }
    return wave_sum(part) + bw[0];
}

// Fused: (a) init X0/VA for locs < |S1| (the only node state ever read);
// (b) per-edge w0 for all 3 lists; E1 edges do the iter-1 aggregation directly from
// RAW inputs (x0[src]=nodes*valid, mv0[src]=mean(valid)); E2/E3 get w0 stored.
__global__ void fused_kernel(const int* __restrict__ counters, const int* __restrict__ l2n,
                             const float* __restrict__ nodes, const float* __restrict__ valid,
                             float* __restrict__ X0, float* __restrict__ VA,
                             int4* __restrict__ lists, const float* __restrict__ ea_g,
                             const float* __restrict__ W1, const float* __restrict__ b1,
                             const float* __restrict__ W2, const float* __restrict__ b2,
                             const float* __restrict__ Wg, const float* __restrict__ bg,
                             const float* __restrict__ Ww, const float* __restrict__ bw,
                             float* __restrict__ agg0)
{
    int tid = blockIdx.x * 256 + threadIdx.x;
    int nthr = (int)gridDim.x * 256;
    int nS1 = counters[4]; if (nS1 > MAXLOC) nS1 = MAXLOC;
    for (int loc = tid; loc < nS1; loc += nthr) {
        int node = l2n[loc];
        const float4* nv = (const float4*)(valid + (size_t)node * LF);
        const float4* nx = (const float4*)(nodes + (size_t)node * LF);
        float4* X0v = (float4*)(X0 + (size_t)loc * LF);
        float4* V0v = (float4*)(VA + (size_t)loc * LF);
        #pragma unroll
        for (int k = 0; k < 12; ++k) {
            float4 v = nv[k], x = nx[k];
            x.x *= v.x; x.y *= v.y; x.z *= v.z; x.w *= v.w;
            X0v[k] = x; V0v[k] = v;
        }
    }
    int c0 = counters[0]; c0 = (c0 > CAP_E) ? CAP_E : c0;
    int c1 = counters[1]; c1 = (c1 > CAP_E) ? CAP_E : c1;
    int c2 = counters[2]; c2 = (c2 > CAP_E) ? CAP_E : c2;
    int total = c0 + c1 + c2;
    int lane = tid & 63;
    for (int g = tid >> 6; g < total; g += (nthr >> 6)) {
        int4* entp;
        bool isE1 = false;
        if (g < c0)           entp = lists + g;
        else if (g < c0 + c1) entp = lists + CAP_E + (g - c0);
        else                { entp = lists + 2 * CAP_E + (g - c0 - c1); isE1 = true; }
        int4 ent = *entp;
        float w0 = w0_compute((long)ent.z, ea_g, W1, b1, W2, b2, Wg, bg, Ww, bw, lane);
        if (isE1) {
            int s = ent.x;                          // global node id
            int dl = ent.y; if ((unsigned)dl >= MAXLOC) dl = 0;   // local loc
            float v = 0.f, x = 0.f;
            if (lane < 48) {
                v = valid[(size_t)s * LF + lane];
                x = nodes[(size_t)s * LF + lane] * v;
            }
            float mv = wave_sum(v) * (1.0f / 48.0f);
            float sg = sigm_f(mv * w0);
            if (lane < 48) atomicAdd(&agg0[dl * LF + lane], sg * x);
        } else if (lane == 0) {
            entp->w = __float_as_int(w0);           // ids already local
        }
    }
}

// ---- single-block tail: upd1 -> agg2 -> upd2 -> agg3 -> upd3 -> out ----
// Wave-per-node (lane = feature) coalesced rows. Active sets are loc RANGES:
// iter-1 update over locs [0,|S1|); iter-2 update over locs [0,|S2|); node0 = loc 0.
__global__ void __launch_bounds__(1024) tail_kernel(
    const int* __restrict__ counters,
    const int4* __restrict__ lists, const float* __restrict__ X0,
    float* __restrict__ XA, float* __restrict__ XB,
    float* __restrict__ VA, float* __restrict__ VB,
    float* __restrict__ MVA, float* __restrict__ MVB,
    const float* __restrict__ agg0, float* __restrict__ agg1b,
    const float* __restrict__ Wf, const float* __restrict__ bf, float* __restrict__ out)
{
    __shared__ float agg3s[LF];
    int tid = threadIdx.x;
    if (tid < LF) agg3s[tid] = 0.f;
    __syncthreads();

    int c1n = counters[4]; if (c1n > MAXLOC) c1n = MAXLOC;   // |S1|
    int c2n = counters[5]; if (c2n > MAXLOC) c2n = MAXLOC;   // |S2|
    int wave = tid >> 6, lane = tid & 63;
    float wf0 = Wf[0], wf1 = Wf[1], wf2 = Wf[2], bfs = bf[0];

    // iter-1 update: locs [0,|S1|); X0/VA -> XA/VB/MVB  (Xp == Xorig == X0 here)
    for (int loc = wave; loc < c1n; loc += 16) {
        float nh = 0.f, xo = 0.f, vp = 0.f;
        if (lane < 48) {
            nh = agg0[loc * LF + lane];
            xo = X0[loc * LF + lane];
            vp = VA[loc * LF + lane];
        }
        float nv = 1.0f - vp;
        float m = sigm_f(nh * wf0 + xo * wf1 + nv * wf2 + bfs);
        float xn = (1.0f - m) * xo + nv * m * nh;
        float vn = ((xo != xn) || (vp > 0.f)) ? 1.0f : 0.0f;
        if (lane == 0) vn = 0.0f;
        if (lane < 48) { XA[loc * LF + lane] = xn; VB[loc * LF + lane] = vn; }
        float s = (lane < 48) ? vn : 0.f;
        #pragma unroll
        for (int off = 32; off > 0; off >>= 1) s += __shfl_down(s, off, 64);
        if (lane == 0) MVB[loc] = s * (1.0f / 48.0f);
    }
    __syncthreads();

    // iter-2 aggregation: E2 (slot1, local ids), wave-per-edge -> agg1b (~270 edges)
    int cE2 = counters[1]; if (cE2 > CAP_E) cE2 = CAP_E;
    for (int i = wave; i < cE2; i += 16) {
        int4 ent = lists[CAP_E + i];
        if ((unsigned)ent.x >= MAXLOC || (unsigned)ent.y >= MAXLOC) continue;
        float sg = sigm_f(MVB[ent.x] * __int_as_float(ent.w));
        if (lane < 48) atomicAdd(&agg1b[ent.y * LF + lane], sg * XA[ent.x * LF + lane]);
    }
    __syncthreads();

    // iter-2 update: locs [0,|S2|); XA/VB -> XB/VA/MVA  (Xorig = X0)
    for (int loc = wave; loc < c2n; loc += 16) {
        float nh = 0.f, xo = 0.f, vp = 0.f, xorig = 0.f;
        if (lane < 48) {
            nh = agg1b[loc * LF + lane];
            xo = XA[loc * LF + lane];
            vp = VB[loc * LF + lane];
            xorig = X0[loc * LF + lane];
        }
        float nv = 1.0f - vp;
        float m = sigm_f(nh * wf0 + xo * wf1 + nv * wf2 + bfs);
        float xn = (1.0f - m) * xo + nv * m * nh;
        float vn = ((xorig != xn) || (vp > 0.f)) ? 1.0f : 0.0f;
        if (lane == 0) vn = 0.0f;
        if (lane < 48) { XB[loc * LF + lane] = xn; VA[loc * LF + lane] = vn; }
        float s = (lane < 48) ? vn : 0.f;
        #pragma unroll
        for (int off = 32; off > 0; off >>= 1) s += __shfl_down(s, off, 64);
        if (lane == 0) MVA[loc] = s * (1.0f / 48.0f);
    }
    __syncthreads();

    // iter-3 aggregation: E3 (slot0, local ids), dst = node 0 -> LDS accumulator
    int cE3 = counters[0]; if (cE3 > CAP_E) cE3 = CAP_E;
    for (int i = wave; i < cE3; i += 16) {
        int4 ent = lists[i];
        if ((unsigned)ent.x >= MAXLOC) continue;
        float sg = sigm_f(MVA[ent.x] * __int_as_float(ent.w));
        if (lane < 48) atomicAdd(&agg3s[lane], sg * XB[ent.x * LF + lane]);
    }
    __syncthreads();

    // iter-3 update for node 0 (= loc 0 by construction) -> output row
    if (tid < 48) {
        float nh = agg3s[tid];
        float xo = XB[tid];          // loc 0 row
        float vp = VA[tid];
        float nv = 1.0f - vp;
        float m = sigm_f(nh * wf0 + xo * wf1 + nv * wf2 + bfs);
        out[tid] = (1.0f - m) * xo + nv * m * nh;
    }
}

extern "C" void kernel_launch(void* const* d_in, const int* in_sizes, int n_in,
                              void* d_out, int out_size, void* d_ws, size_t ws_size,
                              hipStream_t stream)
{
    (void)in_sizes; (void)n_in; (void)out_size;
    const float* nodes = (const float*)d_in[0];
    const int*   eidx  = (const int*)d_in[1];     // (2,E) int32
    const float* eattr = (const float*)d_in[2];
    const float* valid = (const float*)d_in[3];
    // d_in[4]=r, d_in[5]=fx unused by reference
    const float* W1 = (const float*)d_in[6];
    const float* b1 = (const float*)d_in[7];
    const float* W2 = (const float*)d_in[8];
    const float* b2 = (const float*)d_in[9];
    const float* Wg = (const float*)d_in[10];
    const float* bg = (const float*)d_in[11];
    const float* Ww = (const float*)d_in[12];
    const float* bw = (const float*)d_in[13];
    const float* Wf = (const float*)d_in[14];
    const float* bf = (const float*)d_in[15];
    const int* src = eidx;
    const int* dst = eidx + NE;

    char* ws = (char*)d_ws;
    size_t off = 0;
    auto alloc = [&](size_t bytes) -> char* {
        char* p = ws + off;
        off += (bytes + 255) & ~(size_t)255;
        return p;
    };
    // counters + per-partition bcnt contiguous -> single hipMemsetAsync (~400 KB)
    char*     zb = alloc(256 + (size_t)NPART * NBKT * 4);
    int*      counters = (int*)zb;                // [0..5], see lvl2_kernel
    int*      bcnt = (int*)(zb + 256);            // [NPART][NBKT] counts
    int2*     bkt = (int2*)alloc((size_t)NPART * NBKT * BCAPP * 8);   // 51.2 MB
    int*      n2l = (int*)alloc((size_t)NN * 4);
    int*      l2n = (int*)alloc((size_t)MAXLOC * 4);
    int4*     lists = (int4*)alloc((size_t)3 * CAP_E * 16); // slot0=E3, slot1=E2, slot2=E1
    float*    X0 = (float*)alloc((size_t)MAXLOC * LF * 4);
    float*    XA = (float*)alloc((size_t)MAXLOC * LF * 4);
    float*    XB = (float*)alloc((size_t)MAXLOC * LF * 4);
    float*    VA = (float*)alloc((size_t)MAXLOC * LF * 4);
    float*    VB = (float*)alloc((size_t)MAXLOC * LF * 4);
    float*    MVA = (float*)alloc((size_t)MAXLOC * 4);
    float*    MVB = (float*)alloc((size_t)MAXLOC * 4);
    float*    agg = (float*)alloc((size_t)2 * MAXLOC * LF * 4); // agg0 | agg1b
    if (off > ws_size) return;   // ~59 MB needed; fail loudly rather than corrupt
    float* agg0  = agg;
    float* agg1b = agg + MAXLOC * LF;

    hipMemsetAsync(zb, 0, 256 + (size_t)NPART * NBKT * 4, stream);

    // ONE full-edge scan: XCD-private dst-buckets + E3 capture + agg zero-init.
    scatter_kernel<<<NE / 4 / 256, 256, 0, stream>>>(src, dst, bcnt, bkt, (float4*)agg,
                                                     lists, counters);
    // Level 2: S2/S1 sets, locs, E2 list, local-id rewrite (single block, ~9k probes).
    lvl2_kernel<<<1, 1024, 0, stream>>>(src, bcnt, bkt, lists, counters, n2l, l2n);
    // Level 1: wide sub-bucket probe of S1 nodes -> E1 list (~143k probes).
    lvl1_kernel<<<320, 256, 0, stream>>>(src, bcnt, bkt, l2n, lists + 2 * CAP_E, counters);
    // init + per-edge w0 + iter-1 aggregation from raw inputs.
    fused_kernel<<<1024, 256, 0, stream>>>(counters, l2n, nodes, valid,
                                           X0, VA, lists, eattr,
                                           W1, b1, W2, b2, Wg, bg, Ww, bw, agg0);
    // iterations 1-3 updates/aggregations + output.
    tail_kernel<<<1, 1024, 0, stream>>>(counters, lists, X0,
                                        XA, XB, VA, VB, MVA, MVB,
                                        agg0, agg1b, Wf, bf, (float*)d_out);
}